// Round 6
// baseline (1030.159 us; speedup 1.0000x reference)
//
#include <hip/hip_runtime.h>
#include <math.h>

// -----------------------------------------------------------------------------
// DFSPH divergence-solve, block-aggregated binning + sort-based reduce.
//   memset: zero cursor + done counters (one hipMemsetAsync, ~2MB).
//   bin(+pre fused): 8192 edges/block in 4 LDS sub-batches of 2048.
//           Pass 0 (fused pre): block's 256-particle slice -> pre2 table.
//           Pass 1 (count): read nbr[i] only (L3-hot), histogram 512 buckets.
//           ONE cursor claim per (block,bucket) for all 8192 edges -> mean
//           global run 16 records (192B; was 4/48B) so most 64B sectors are
//           single-writer (r5 measured 172MB written for 101MB payload at
//           run=4). Then 4x {rank, wave0-scan, LDS counting sort, writeout
//           (1 ds_read_b128 + 1 dwordx3/record)}. Payload still split into
//           NR=8 pseudo-XCD regions keyed by blockIdx&7 (same-XCD L2 merges
//           partial sectors). 12B record {jli=(j<<9)|li, gx, gy}.
//   reduce(+fin fused): register double-buffered NT payload loads; pre2[j]
//           gathers issued early; counting sort per TILE=1024 into 6 SoA b32
//           arrays; contiguous per-particle register accumulate. Epilogue
//           writes slice partials (normal stores), __threadfence, per-bucket
//           done counter; LAST of the NSLICE=4 slice-blocks sums the 4 slices
//           (L2/L3-hot) and writes out[N,5] -- no separate fin dispatch.
// 2 real dispatches + 1 tiny memset (was 4 dispatches); ~130us/iter of
// pre+fin+launch-boundary residue was the 2nd-largest cost after bin.
// Fallback (tiny ws): pre + direct global float atomics + fin.
// -----------------------------------------------------------------------------

#define PB        512
#define PB_SHIFT  9
#define NR        8       // bin payload regions (pseudo-XCD via blockIdx&7)
#define NSLICE    4       // partials slices (reduce block covers 2 regions)
#define CSTRIDE   16      // ints per cursor -> 64B, one cacheline each
#define SB        4       // bin sub-batches per block
#define SBE       2048    // edges per sub-batch
#define BIN_EDGES (SB * SBE)   // 8192
#define TILE      1024    // records per reduce sort round

typedef float v2f __attribute__((ext_vector_type(2)));
typedef float v4f __attribute__((ext_vector_type(4)));

// LDS-only barrier: orders DS ops across the block WITHOUT draining vmcnt,
// so global loads/stores stay in flight across phases.
__device__ __forceinline__ void ldsbar() {
    asm volatile("s_waitcnt lgkmcnt(0)" ::: "memory");
    __builtin_amdgcn_s_barrier();
    asm volatile("" ::: "memory");
}

static inline size_t align256(size_t x) { return (x + 255) & ~(size_t)255; }

__global__ __launch_bounds__(256) void pre_kernel(   // fallback path only
    const float*  __restrict__ area,
    const float*  __restrict__ actualArea,
    const float*  __restrict__ restDensity,
    const float*  __restrict__ density,
    const float*  __restrict__ pressure2,
    const float2* __restrict__ vel,
    const float2* __restrict__ accel,
    float4* __restrict__ pre2,
    float*  __restrict__ accz, int nacc,
    int n) {
    int t = blockIdx.x * blockDim.x + threadIdx.x;
    int stride = gridDim.x * blockDim.x;
    for (int k = t; k < nacc; k += stride) accz[k] = 0.f;
    if (t >= n) return;
    float m  = area[t] * restDensity[t];
    float dr = density[t] * restDensity[t];
    float p  = pressure2[t] / (dr * dr);
    float aa = actualArea[t];
    float2 v  = vel[t];
    float2 ac = accel[t];
    pre2[2 * (size_t)t]     = make_float4(p, m / aa, aa, aa * aa / m);
    pre2[2 * (size_t)t + 1] = make_float4(v.x, v.y, ac.x, ac.y);
}

__global__ __launch_bounds__(256) void bin_kernel(
    const int*    __restrict__ nbr,
    const float*  __restrict__ rad,
    const float2* __restrict__ dirs,
    const float*  __restrict__ supp,
    const float*  __restrict__ area,
    const float*  __restrict__ actualArea,
    const float*  __restrict__ restDensity,
    const float*  __restrict__ density,
    const float*  __restrict__ pressure2,
    const float2* __restrict__ vel,
    const float2* __restrict__ accel,
    float4*       __restrict__ pre2,
    int doPre, int ppb, int n,
    int*          __restrict__ cursor,
    unsigned int* __restrict__ pay32,
    int cap, int nb, int estart, int eend, int E) {
    __shared__ float4 srec[SBE];         // 32 KB sorted {jli,gx,gy,gd}
    __shared__ int ltot[512];            //  2 KB total counts (all sub-batches)
    __shared__ int lcount[512];          //  2 KB per-sub-batch counts
    __shared__ int lclaim[512];          //  2 KB claimed global record base
    __shared__ int lstart[512];          //  2 KB exclusive scan (LDS slot)
    __shared__ int lprev[512];           //  2 KB records consumed so far
    int tid = threadIdx.x;
    int x   = blockIdx.x & (NR - 1);     // pseudo-XCD region

    // pass 0 (fused pre): this block's particle slice -> pre2
    if (doPre) {
        int pbase = blockIdx.x * ppb;
        int pend  = pbase + ppb; if (pend > n) pend = n;
        for (int t = pbase + tid; t < pend; t += 256) {
            float m  = area[t] * restDensity[t];
            float dr = density[t] * restDensity[t];
            float p  = pressure2[t] / (dr * dr);
            float aa = actualArea[t];
            float2 v  = vel[t];
            float2 ac = accel[t];
            pre2[2 * (size_t)t]     = make_float4(p, m / aa, aa, aa * aa / m);
            pre2[2 * (size_t)t + 1] = make_float4(v.x, v.y, ac.x, ac.y);
        }
    }

    for (int k = tid; k < 512; k += 256) { ltot[k] = 0; lprev[k] = 0; }
    ldsbar();
    int e0 = estart + blockIdx.x * BIN_EDGES;

    // pass 1 (count): i-indices only; coalesced, L3-hot
    for (int k = tid; k < BIN_EDGES; k += 256) {
        int e = e0 + k;
        if (e < eend) {
            int i = __builtin_nontemporal_load(nbr + e);
            atomicAdd(&ltot[i >> PB_SHIFT], 1);
        }
    }
    ldsbar();
    // one cursor claim per (block,bucket) for ALL sub-batches -> runs of ~16
    for (int k = tid; k < nb; k += 256) {
        int c = ltot[k];
        lclaim[k] = c ? atomicAdd(&cursor[(size_t)(k * NR + x) * CSTRIDE], c) : 0;
    }
    ldsbar();

    float h  = supp[0];
    float kc = 20.0f * (7.0f / 3.14159265358979323846f) / (h * h * h);
    int cap3  = cap * 3;       // dwords per region
    int cap24 = cap * 3 * NR;  // dwords per bucket

    for (int sb = 0; sb < SB; ++sb) {
        for (int k = tid; k < 512; k += 256) lcount[k] = 0;
        ldsbar();
        int es = e0 + sb * SBE + tid;
        // rank: stream 8 edges/thread into registers
        int jj[8]; float qq[8]; v2f dd[8]; int pk[8];
#pragma unroll
        for (int k = 0; k < 8; ++k) {
            int e = es + k * 256;
            pk[k] = -1; jj[k] = 0; qq[k] = 0.f; dd[k] = (v2f){0.f, 0.f};
            if (e < eend) {
                jj[k] = __builtin_nontemporal_load(nbr + E + e);
                qq[k] = __builtin_nontemporal_load(rad + e);
                dd[k] = __builtin_nontemporal_load((const v2f*)dirs + e);
                int i = __builtin_nontemporal_load(nbr + e);
                int b = i >> PB_SHIFT;
                int r = atomicAdd(&lcount[b], 1);
                pk[k] = (b << 21) | ((i & (PB - 1)) << 12) | r;
            }
        }
        ldsbar();
        // exclusive prefix scan of 512 counts by wave 0
        if (tid < 64) {
            int running = 0;
            for (int c = 0; c < 8; ++c) {
                int orig = lcount[c * 64 + tid];
                int v = orig;
#pragma unroll
                for (int off = 1; off < 64; off <<= 1) {
                    int u = __shfl_up(v, off, 64);
                    if (tid >= off) v += u;
                }
                lstart[c * 64 + tid] = running + v - orig;
                running += __shfl(v, 63, 64);
            }
        }
        ldsbar();
        // scatter: compute gradient, write 16B record into bucket-sorted LDS
#pragma unroll
        for (int k = 0; k < 8; ++k) {
            if (pk[k] < 0) continue;
            int b  = pk[k] >> 21;
            int li = (pk[k] >> 12) & (PB - 1);
            int r  = pk[k] & 2047;
            float  q = qq[k];
            v2f    d = dd[k];
            float om  = 1.0f - q;
            float mag = kc * q * om * om * om;
            float gx = -d.x * mag;
            float gy = -d.y * mag;
            int g  = lclaim[b] + lprev[b] + r;
            int gd = (g < cap) ? (b * cap24 + x * cap3 + g * 3) : -1;  // 8-sigma
            srec[lstart[b] + r] = make_float4(
                __int_as_float((jj[k] << PB_SHIFT) | li), gx, gy,
                __int_as_float(gd));
        }
        ldsbar();
        // writeout: contiguous runs; same-region neighbors share an XCD L2
        int total = lstart[511] + lcount[511];
        for (int r = tid; r < total; r += 256) {
            float4 rec = srec[r];
            int gd = __float_as_int(rec.w);
            if (gd >= 0) {
                uint3 w = make_uint3(__float_as_uint(rec.x),
                                     __float_as_uint(rec.y),
                                     __float_as_uint(rec.z));
                *(uint3*)(pay32 + gd) = w;
            }
        }
        for (int k = tid; k < 512; k += 256) lprev[k] += lcount[k];
        ldsbar();   // srec reads + lprev update done before next sub-batch
    }
}

__global__ __launch_bounds__(256) void reduce_kernel(
    const unsigned int* __restrict__ pay32,
    const int*    __restrict__ cursor, int cap,
    const float4* __restrict__ pre2,
    const float*  __restrict__ dtp,
    float*        __restrict__ partials,
    const float*  __restrict__ area,
    const float*  __restrict__ actualArea,
    const float*  __restrict__ restDensity,
    float*        __restrict__ out,
    int*          __restrict__ done,
    int accum, int fuse, int n) {
    __shared__ float s7[6][TILE];        // 24 KB SoA expanded records
    __shared__ int   lhist[PB];          //  2 KB counts
    __shared__ int   lofs[PB];           //  2 KB offsets -> cursors
    __shared__ float ptab[PB];           //  2 KB per-particle p
    __shared__ int   lastFlag;
    int b   = blockIdx.x >> 2;
    int sb  = blockIdx.x & (NSLICE - 1);
    int tid = threadIdx.x;

    int p0 = (b << PB_SHIFT) + tid;
    int p1 = p0 + 256;
    float pi0 = (p0 < n) ? pre2[2 * (size_t)p0].x : 0.f;
    float pi1 = (p1 < n) ? pre2[2 * (size_t)p1].x : 0.f;
    ptab[tid] = pi0; ptab[tid + 256] = pi1;
    float a0[7] = {0.f, 0.f, 0.f, 0.f, 0.f, 0.f, 0.f};
    float a1[7] = {0.f, 0.f, 0.f, 0.f, 0.f, 0.f, 0.f};

    int r0 = tid * 4;                    // this thread's 4 records per tile
    for (int rg = 0; rg < 2; ++rg) {
        int s = sb + rg * NSLICE;        // regions sb and sb+4
        int cnt = cursor[(size_t)(b * NR + s) * CSTRIDE];
        if (cnt > cap) cnt = cap;
        size_t RB = (size_t)(b * NR + s) * cap * 3;  // dword base of region

        v4f c0v, c1v, c2v, n0v, n1v, n2v;
        if (cnt > 0) {
            int rb = r0;
            int rc_ = (rb + 4 <= cap) ? rb : (cap - 4);
            const v4f* g = (const v4f*)(pay32 + RB + (size_t)rc_ * 3);
            c0v = __builtin_nontemporal_load(g);
            c1v = __builtin_nontemporal_load(g + 1);
            c2v = __builtin_nontemporal_load(g + 2);
        }
        for (int T = 0; T < cnt; T += TILE) {
            lhist[tid] = 0; lhist[tid + 256] = 0;
            // issue next tile's nt loads (in flight across whole pipeline)
            if (T + TILE < cnt) {
                int rb = T + TILE + r0;
                int rc_ = (rb + 4 <= cap) ? rb : (cap - 4);
                const v4f* g = (const v4f*)(pay32 + RB + (size_t)rc_ * 3);
                n0v = __builtin_nontemporal_load(g);
                n1v = __builtin_nontemporal_load(g + 1);
                n2v = __builtin_nontemporal_load(g + 2);
            }
            // decode 4 records; issue pre2[j] gathers EARLY (normal loads: L2)
            int rb = T + r0;
            bool v0 = rb < cnt, v1 = rb + 1 < cnt, v2 = rb + 2 < cnt, v3 = rb + 3 < cnt;
            int jli0 = __float_as_int(c0v.x); float gx0 = c0v.y, gy0 = c0v.z;
            int jli1 = __float_as_int(c0v.w); float gx1 = c1v.x, gy1 = c1v.y;
            int jli2 = __float_as_int(c1v.z); float gx2 = c1v.w, gy2 = c2v.x;
            int jli3 = __float_as_int(c2v.y); float gx3 = c2v.z, gy3 = c2v.w;
            int li0 = jli0 & (PB - 1), li1 = jli1 & (PB - 1);
            int li2 = jli2 & (PB - 1), li3 = jli3 & (PB - 1);
            size_t j0 = v0 ? (size_t)(jli0 >> PB_SHIFT) : 0;
            size_t j1 = v1 ? (size_t)(jli1 >> PB_SHIFT) : 0;
            size_t j2 = v2 ? (size_t)(jli2 >> PB_SHIFT) : 0;
            size_t j3 = v3 ? (size_t)(jli3 >> PB_SHIFT) : 0;
            float4 ja0 = pre2[2 * j0], jb0 = pre2[2 * j0 + 1];
            float4 ja1 = pre2[2 * j1], jb1 = pre2[2 * j1 + 1];
            float4 ja2 = pre2[2 * j2], jb2 = pre2[2 * j2 + 1];
            float4 ja3 = pre2[2 * j3], jb3 = pre2[2 * j3 + 1];
            ldsbar();          // hist zeros + ptab visible
            if (v0) atomicAdd(&lhist[li0], 1);
            if (v1) atomicAdd(&lhist[li1], 1);
            if (v2) atomicAdd(&lhist[li2], 1);
            if (v3) atomicAdd(&lhist[li3], 1);
            ldsbar();
            // exclusive prefix scan of 512 counts by wave 0
            if (tid < 64) {
                int running = 0;
                for (int c = 0; c < 8; ++c) {
                    int orig = lhist[c * 64 + tid];
                    int v = orig;
#pragma unroll
                    for (int off = 1; off < 64; off <<= 1) {
                        int u = __shfl_up(v, off, 64);
                        if (tid >= off) v += u;
                    }
                    lofs[c * 64 + tid] = running + v - orig;
                    running += __shfl(v, 63, 64);
                }
            }
            ldsbar();
            // scatter: expand into 6 SoA b32 arrays in particle-sorted order
#define SCAT(vv, li, jaa, jbb, gxx, gyy)                                     \
            if (vv) {                                                        \
                int sl = atomicAdd(&lofs[li], 1);                            \
                float C0 = jaa.z * gxx;                                      \
                float C1 = jaa.z * gyy;                                      \
                s7[0][sl] = C0;                                              \
                s7[1][sl] = C1;                                              \
                s7[2][sl] = jaa.w * (gxx * gxx + gyy * gyy);                 \
                s7[3][sl] = -(ptab[li] + jaa.x) * jaa.y;                     \
                s7[4][sl] = jbb.x * C0 + jbb.y * C1;                         \
                s7[5][sl] = jbb.z * C0 + jbb.w * C1;                         \
            }
            SCAT(v0, li0, ja0, jb0, gx0, gy0)
            SCAT(v1, li1, ja1, jb1, gx1, gy1)
            SCAT(v2, li2, ja2, jb2, gx2, gy2)
            SCAT(v3, li3, ja3, jb3, gx3, gy3)
#undef SCAT
            ldsbar();
            // gather: contiguous segment per particle, pure-sum b32 reads
            {
                int e0 = lofs[tid], h0 = lhist[tid];
                for (int r = e0 - h0; r < e0; ++r) {
                    float C0 = s7[0][r], C1 = s7[1][r], rc = s7[3][r];
                    a0[0] += C0; a0[1] += C1; a0[2] += s7[2][r];
                    a0[3] += rc * C0; a0[4] += rc * C1;
                    a0[5] += s7[4][r]; a0[6] += s7[5][r];
                }
                int e1 = lofs[tid + 256], h1 = lhist[tid + 256];
                for (int r = e1 - h1; r < e1; ++r) {
                    float C0 = s7[0][r], C1 = s7[1][r], rc = s7[3][r];
                    a1[0] += C0; a1[1] += C1; a1[2] += s7[2][r];
                    a1[3] += rc * C0; a1[4] += rc * C1;
                    a1[5] += s7[4][r]; a1[6] += s7[5][r];
                }
            }
            ldsbar();          // gather done before next tile zeroes lhist
            c0v = n0v; c1v = n1v; c2v = n2v;
        }
    }

    // epilogue: dt scaling + linear i-side corrections; 8-float padded record
    float dt  = dtp[0];
    float dt2 = dt * dt;
    v4f* dst = (v4f*)(partials + ((size_t)b * NSLICE + sb) * (PB * 8));
    {
        float4 va = (p0 < n) ? pre2[2 * (size_t)p0 + 1]
                             : make_float4(0.f, 0.f, 0.f, 0.f);
        float src = dt  * (a0[5] - (va.x * a0[0] + va.y * a0[1]));
        float ker = dt2 * ((va.z * a0[0] + va.w * a0[1]) - a0[6]);
        v4f w0 = {a0[0], a0[1], a0[2], a0[3]};
        v4f w1 = {a0[4], src, ker, 0.f};
        v4f* d = dst + (size_t)tid * 2;
        if (accum) { v4f o0 = d[0], o1 = d[1]; d[0] = w0 + o0; d[1] = w1 + o1; }
        else       { d[0] = w0; d[1] = w1; }
    }
    {
        float4 va = (p1 < n) ? pre2[2 * (size_t)p1 + 1]
                             : make_float4(0.f, 0.f, 0.f, 0.f);
        float src = dt  * (a1[5] - (va.x * a1[0] + va.y * a1[1]));
        float ker = dt2 * ((va.z * a1[0] + va.w * a1[1]) - a1[6]);
        v4f w0 = {a1[0], a1[1], a1[2], a1[3]};
        v4f w1 = {a1[4], src, ker, 0.f};
        v4f* d = dst + (size_t)(tid + 256) * 2;
        if (accum) { v4f o0 = d[0], o1 = d[1]; d[0] = w0 + o0; d[1] = w1 + o1; }
        else       { d[0] = w0; d[1] = w1; }
    }

    if (!fuse) return;
    // fused fin: last slice-block of this bucket sums 4 slices, writes out.
    __threadfence();
    __syncthreads();
    if (tid == 0) lastFlag = (atomicAdd(&done[b], 1) == NSLICE - 1) ? 1 : 0;
    __syncthreads();
    if (!lastFlag) return;
    __threadfence();
    const v4f* pbase = (const v4f*)(partials + (size_t)b * NSLICE * (PB * 8));
#pragma unroll
    for (int k = 0; k < 2; ++k) {
        int idx = tid + (k << 8);
        int p   = (b << PB_SHIFT) + idx;
        if (p >= n) continue;
        float t0 = 0, t1 = 0, t2 = 0, t3 = 0, t4 = 0, t5 = 0, t6 = 0;
        for (int sl = 0; sl < NSLICE; ++sl) {
            v4f q0 = pbase[(size_t)sl * (PB * 2) + 2 * idx];
            v4f q1 = pbase[(size_t)sl * (PB * 2) + 2 * idx + 1];
            t0 += q0.x; t1 += q0.y; t2 += q0.z; t3 += q0.w;
            t4 += q1.x; t5 += q1.y; t6 += q1.z;
        }
        float fac  = -dt2 * actualArea[p];
        float mass = area[p] * restDensity[p];
        float alpha = fac / mass * (t0 * t0 + t1 * t1) + fac * t2;
        float* o = out + (size_t)p * 5;
        o[0] = alpha; o[1] = t3; o[2] = t4; o[3] = t5; o[4] = t6;
    }
}

// ---- fallback: direct global float atomics ----
__global__ void edge_kernel(const int* __restrict__ nbr,
                            const float* __restrict__ rad,
                            const float2* __restrict__ dirs,
                            const float4* __restrict__ pre2,
                            const float* __restrict__ supp,
                            const float* __restrict__ dtp,
                            float* __restrict__ acc, int E) {
    int e = blockIdx.x * blockDim.x + threadIdx.x;
    if (e >= E) return;
    float h = supp[0], dt = dtp[0];
    float kc = 20.0f * (7.0f / 3.14159265358979323846f) / (h * h * h);
    int i = nbr[e];
    int j = nbr[E + e];
    float  q = rad[e];
    float2 d = dirs[e];
    float om  = 1.0f - q;
    float mag = kc * q * om * om * om;
    float gx = -d.x * mag;
    float gy = -d.y * mag;
    float g2 = gx * gx + gy * gy;
    float4 ja = pre2[2 * (size_t)j];      // {p, r, aa, aa2m}
    float4 jb = pre2[2 * (size_t)j + 1];
    float4 ia = pre2[2 * (size_t)i];
    float4 ib = pre2[2 * (size_t)i + 1];
    float aaj = ja.z;
    float m   = ja.y * aaj;
    float pp  = -m * (ia.x + ja.x);
    float vdotg = (ib.x - jb.x) * gx + (ib.y - jb.y) * gy;
    float adotg = (ib.z - jb.z) * gx + (ib.w - jb.w) * gy;
    float* base = acc + (size_t)i * 8;
    atomicAdd(base + 0, aaj * gx);
    atomicAdd(base + 1, aaj * gy);
    atomicAdd(base + 2, ja.w * g2);
    atomicAdd(base + 3, pp * gx);
    atomicAdd(base + 4, pp * gy);
    atomicAdd(base + 5, -dt * aaj * vdotg);
    atomicAdd(base + 6, dt * dt * aaj * adotg);
}

__global__ __launch_bounds__(256) void fin_kernel(   // fallback path only
    const float* __restrict__ area,
    const float* __restrict__ actualArea,
    const float* __restrict__ restDensity,
    const float* __restrict__ dtp,
    const float* __restrict__ data,
    float* __restrict__ out, int n) {
    int t = blockIdx.x * blockDim.x + threadIdx.x;
    if (t >= n) return;
    const float* a = data + (size_t)t * 8;
    float s0 = a[0], s1 = a[1], s2 = a[2], s3 = a[3];
    float s4 = a[4], s5 = a[5], s6 = a[6];
    float dt   = dtp[0];
    float fac  = -dt * dt * actualArea[t];
    float mass = area[t] * restDensity[t];
    float alpha = fac / mass * (s0 * s0 + s1 * s1) + fac * s2;
    float* o = out + (size_t)t * 5;
    o[0] = alpha;
    o[1] = s3;
    o[2] = s4;
    o[3] = s5;
    o[4] = s6;
}

extern "C" void kernel_launch(void* const* d_in, const int* in_sizes, int n_in,
                              void* d_out, int out_size, void* d_ws, size_t ws_size,
                              hipStream_t stream) {
    const float* area        = (const float*)d_in[0];
    const float* actualArea  = (const float*)d_in[1];
    const float* restDensity = (const float*)d_in[2];
    const float* density     = (const float*)d_in[3];
    const float* pressure2   = (const float*)d_in[4];
    const float2* vel        = (const float2*)d_in[5];
    const float2* accel      = (const float2*)d_in[6];
    const float* rad         = (const float*)d_in[7];
    const float2* dirs       = (const float2*)d_in[8];
    const int*   nbr         = (const int*)d_in[9];
    const float* supp        = (const float*)d_in[10];
    const float* dtp         = (const float*)d_in[11];
    float* out = (float*)d_out;

    int N = in_sizes[0];
    int E = in_sizes[7];
    int nb = (N + PB - 1) >> PB_SHIFT;   // 512 for N=262144

    size_t sz_cur   = (size_t)nb * NR * CSTRIDE * 8 * sizeof(int);
    size_t sz_done  = (size_t)nb * sizeof(int);
    size_t off_pre  = align256(sz_cur + sz_done);
    size_t sz_pre   = (size_t)N * 8 * sizeof(float);
    size_t off_part = align256(off_pre + sz_pre);
    size_t sz_partA = (size_t)nb * NSLICE * PB * 8 * sizeof(float);
    size_t sz_partB = (size_t)N * 8 * sizeof(float);   // fallback acc layout
    size_t sz_part  = sz_partA > sz_partB ? sz_partA : sz_partB;
    size_t off_pay  = align256(off_part + sz_part);

    int* cursor     = (int*)d_ws;
    int* done       = (int*)((char*)d_ws + sz_cur);
    float4* pre2    = (float4*)((char*)d_ws + off_pre);
    float* partials = (float*)((char*)d_ws + off_part);

    // pick chunking so payload fits (12B records, NR regions per bucket)
    int nchunk = 0, cap = 0;
    if (nb <= 512 && ws_size > off_pay) {
        for (int c = 1; c <= 8; c *= 2) {
            long long Ec = (E + c - 1) / c;
            double mean = (double)Ec / ((double)nb * NR);
            long long need = (long long)(mean + 8.0 * sqrt(mean) + 64.0);
            need = (need + 63) & ~63ll;
            if (off_pay + (size_t)nb * NR * need * 12 <= ws_size) {
                nchunk = c; cap = (int)need; break;
            }
        }
    }

    int bs = 256;
    int grid_n = (N + bs - 1) / bs;
    if (nchunk > 0) {
        unsigned int* pay32 = (unsigned int*)((char*)d_ws + off_pay);
        hipMemsetAsync(d_ws, 0, off_pre, stream);   // cursors + done counters
        int Ec  = (E + nchunk - 1) / nchunk;
        for (int c = 0; c < nchunk; ++c) {
            int es = c * Ec;
            int ee = es + Ec; if (ee > E) ee = E;
            if (es >= ee) break;
            int* curC = cursor + (size_t)c * nb * NR * CSTRIDE;
            int nblk = (ee - es + BIN_EDGES - 1) / BIN_EDGES;
            int ppb  = (N + nblk - 1) / nblk;
            bin_kernel<<<nblk, bs, 0, stream>>>(
                nbr, rad, dirs, supp,
                area, actualArea, restDensity, density, pressure2, vel, accel,
                pre2, (c == 0) ? 1 : 0, ppb, N,
                curC, pay32, cap, nb, es, ee, E);
            reduce_kernel<<<nb * NSLICE, bs, 0, stream>>>(
                pay32, curC, cap, pre2, dtp, partials,
                area, actualArea, restDensity, out, done,
                (c > 0) ? 1 : 0, (c == nchunk - 1) ? 1 : 0, N);
        }
    } else {
        float* acc = partials;  // [N,8] at off_part
        pre_kernel<<<grid_n, bs, 0, stream>>>(
            area, actualArea, restDensity, density, pressure2, vel, accel,
            pre2, acc, N * 8, N);
        edge_kernel<<<(E + bs - 1) / bs, bs, 0, stream>>>(
            nbr, rad, dirs, pre2, supp, dtp, acc, E);
        fin_kernel<<<grid_n, bs, 0, stream>>>(
            area, actualArea, restDensity, dtp, acc, out, N);
    }
}

// Round 7
// 391.945 us; speedup vs baseline: 2.6283x; 2.6283x over previous
//
#include <hip/hip_runtime.h>
#include <math.h>

// -----------------------------------------------------------------------------
// DFSPH divergence-solve, block-aggregated binning + sort-based reduce.
//   memset: zero cursors (one hipMemsetAsync, ~2MB, stream-ordered).
//   bin(+pre fused): 8192 edges/block in 4 LDS sub-batches of 2048.
//           Pass 0 (fused pre): block's particle slice -> pre2 (bin never
//           reads pre2; reduce launches after bin -> no ordering hazard).
//           Pass 1 (count): read nbr[i] only (normal loads, L2-cached for the
//           rank pass), histogram 512 buckets. ONE cursor claim per
//           (block,bucket) for all 8192 edges -> mean global run 16 records
//           (192B; r5 measured 172MB written for a 101MB payload at run=4 ->
//           partial-sector double eviction). Then 4x {rank, wave0-scan, LDS
//           counting sort, writeout (1 ds_read_b128 + 1 dwordx3/record)};
//           lclaim advances in place after each sub-batch (no lprev -> LDS
//           exactly 40KB -> 4 blocks/CU, same occupancy as r5).
//           Payload split into NR=8 pseudo-XCD regions keyed by blockIdx&7.
//           12B record {jli=(j<<9)|li, gx, gy}.
//   reduce: r5 EXACT (r6's fused-fin __threadfence stretched reduce 6x:
//           device-scope fence = per-block L2 writeback/invalidate nuking
//           sibling blocks' pre2 gather locality). Register double-buffered
//           NT payload loads; early pre2[j] gathers; counting sort per
//           TILE=1024 into 6 SoA b32 arrays; contiguous per-particle register
//           accumulate; NT epilogue stores.
//   fin:    separate kernel, 2x v4f NT loads per slice, 4 slices.
// Fallback (tiny ws): pre + direct global float atomics + fin.
// -----------------------------------------------------------------------------

#define PB        512
#define PB_SHIFT  9
#define NR        8       // bin payload regions (pseudo-XCD via blockIdx&7)
#define NSLICE    4       // partials slices (reduce block covers 2 regions)
#define CSTRIDE   16      // ints per cursor -> 64B, one cacheline each
#define SB        4       // bin sub-batches per block
#define SBE       2048    // edges per sub-batch
#define BIN_EDGES (SB * SBE)   // 8192
#define TILE      1024    // records per reduce sort round

typedef float v2f __attribute__((ext_vector_type(2)));
typedef float v4f __attribute__((ext_vector_type(4)));

// LDS-only barrier: orders DS ops across the block WITHOUT draining vmcnt,
// so global loads/stores stay in flight across phases.
__device__ __forceinline__ void ldsbar() {
    asm volatile("s_waitcnt lgkmcnt(0)" ::: "memory");
    __builtin_amdgcn_s_barrier();
    asm volatile("" ::: "memory");
}

static inline size_t align256(size_t x) { return (x + 255) & ~(size_t)255; }

__global__ __launch_bounds__(256) void pre_kernel(   // fallback path only
    const float*  __restrict__ area,
    const float*  __restrict__ actualArea,
    const float*  __restrict__ restDensity,
    const float*  __restrict__ density,
    const float*  __restrict__ pressure2,
    const float2* __restrict__ vel,
    const float2* __restrict__ accel,
    float4* __restrict__ pre2,
    float*  __restrict__ accz, int nacc,
    int n) {
    int t = blockIdx.x * blockDim.x + threadIdx.x;
    int stride = gridDim.x * blockDim.x;
    for (int k = t; k < nacc; k += stride) accz[k] = 0.f;
    if (t >= n) return;
    float m  = area[t] * restDensity[t];
    float dr = density[t] * restDensity[t];
    float p  = pressure2[t] / (dr * dr);
    float aa = actualArea[t];
    float2 v  = vel[t];
    float2 ac = accel[t];
    pre2[2 * (size_t)t]     = make_float4(p, m / aa, aa, aa * aa / m);
    pre2[2 * (size_t)t + 1] = make_float4(v.x, v.y, ac.x, ac.y);
}

__global__ __launch_bounds__(256) void bin_kernel(
    const int*    __restrict__ nbr,
    const float*  __restrict__ rad,
    const float2* __restrict__ dirs,
    const float*  __restrict__ supp,
    const float*  __restrict__ area,
    const float*  __restrict__ actualArea,
    const float*  __restrict__ restDensity,
    const float*  __restrict__ density,
    const float*  __restrict__ pressure2,
    const float2* __restrict__ vel,
    const float2* __restrict__ accel,
    float4*       __restrict__ pre2,
    int doPre, int ppb, int n,
    int*          __restrict__ cursor,
    unsigned int* __restrict__ pay32,
    int cap, int nb, int estart, int eend, int E) {
    __shared__ float4 srec[SBE];         // 32 KB sorted {jli,gx,gy,gd}
    __shared__ int ltot[512];            //  2 KB total counts (all sub-batches)
    __shared__ int lcount[512];          //  2 KB per-sub-batch counts
    __shared__ int lclaim[512];          //  2 KB advancing global record base
    __shared__ int lstart[512];          //  2 KB exclusive scan (LDS slot)
    int tid = threadIdx.x;
    int x   = blockIdx.x & (NR - 1);     // pseudo-XCD region

    // pass 0 (fused pre): this block's particle slice -> pre2
    if (doPre) {
        int pbase = blockIdx.x * ppb;
        int pend  = pbase + ppb; if (pend > n) pend = n;
        for (int t = pbase + tid; t < pend; t += 256) {
            float m  = area[t] * restDensity[t];
            float dr = density[t] * restDensity[t];
            float p  = pressure2[t] / (dr * dr);
            float aa = actualArea[t];
            float2 v  = vel[t];
            float2 ac = accel[t];
            pre2[2 * (size_t)t]     = make_float4(p, m / aa, aa, aa * aa / m);
            pre2[2 * (size_t)t + 1] = make_float4(v.x, v.y, ac.x, ac.y);
        }
    }

    for (int k = tid; k < 512; k += 256) ltot[k] = 0;
    ldsbar();
    int e0 = estart + blockIdx.x * BIN_EDGES;

    // pass 1 (count): i-indices only; normal loads (cache for rank pass)
    for (int k = tid; k < BIN_EDGES; k += 256) {
        int e = e0 + k;
        if (e < eend) atomicAdd(&ltot[nbr[e] >> PB_SHIFT], 1);
    }
    ldsbar();
    // one cursor claim per (block,bucket) for ALL sub-batches -> runs of ~16
    for (int k = tid; k < nb; k += 256) {
        int c = ltot[k];
        lclaim[k] = c ? atomicAdd(&cursor[(size_t)(k * NR + x) * CSTRIDE], c) : 0;
    }
    ldsbar();

    float h  = supp[0];
    float kc = 20.0f * (7.0f / 3.14159265358979323846f) / (h * h * h);
    int cap3  = cap * 3;       // dwords per region
    int cap24 = cap * 3 * NR;  // dwords per bucket

    for (int sb = 0; sb < SB; ++sb) {
        for (int k = tid; k < 512; k += 256) lcount[k] = 0;
        ldsbar();
        int es = e0 + sb * SBE + tid;
        // rank: stream 8 edges/thread into registers
        int jj[8]; float qq[8]; v2f dd[8]; int pk[8];
#pragma unroll
        for (int k = 0; k < 8; ++k) {
            int e = es + k * 256;
            pk[k] = -1; jj[k] = 0; qq[k] = 0.f; dd[k] = (v2f){0.f, 0.f};
            if (e < eend) {
                jj[k] = __builtin_nontemporal_load(nbr + E + e);
                qq[k] = __builtin_nontemporal_load(rad + e);
                dd[k] = __builtin_nontemporal_load((const v2f*)dirs + e);
                int i = nbr[e];                      // L2-hot from pass 1
                int b = i >> PB_SHIFT;
                int r = atomicAdd(&lcount[b], 1);
                pk[k] = (b << 21) | ((i & (PB - 1)) << 12) | r;
            }
        }
        ldsbar();
        // exclusive prefix scan of 512 counts by wave 0
        if (tid < 64) {
            int running = 0;
            for (int c = 0; c < 8; ++c) {
                int orig = lcount[c * 64 + tid];
                int v = orig;
#pragma unroll
                for (int off = 1; off < 64; off <<= 1) {
                    int u = __shfl_up(v, off, 64);
                    if (tid >= off) v += u;
                }
                lstart[c * 64 + tid] = running + v - orig;
                running += __shfl(v, 63, 64);
            }
        }
        ldsbar();
        // scatter: compute gradient, write 16B record into bucket-sorted LDS
#pragma unroll
        for (int k = 0; k < 8; ++k) {
            if (pk[k] < 0) continue;
            int b  = pk[k] >> 21;
            int li = (pk[k] >> 12) & (PB - 1);
            int r  = pk[k] & 2047;
            float  q = qq[k];
            v2f    d = dd[k];
            float om  = 1.0f - q;
            float mag = kc * q * om * om * om;
            float gx = -d.x * mag;
            float gy = -d.y * mag;
            int g  = lclaim[b] + r;
            int gd = (g < cap) ? (b * cap24 + x * cap3 + g * 3) : -1;  // 8-sigma
            srec[lstart[b] + r] = make_float4(
                __int_as_float((jj[k] << PB_SHIFT) | li), gx, gy,
                __int_as_float(gd));
        }
        ldsbar();
        // writeout: contiguous runs; same-region neighbors share an XCD L2
        int total = lstart[511] + lcount[511];
        for (int r = tid; r < total; r += 256) {
            float4 rec = srec[r];
            int gd = __float_as_int(rec.w);
            if (gd >= 0) {
                uint3 w = make_uint3(__float_as_uint(rec.x),
                                     __float_as_uint(rec.y),
                                     __float_as_uint(rec.z));
                *(uint3*)(pay32 + gd) = w;
            }
        }
        // advance claim base past this sub-batch's records
        for (int k = tid; k < 512; k += 256) lclaim[k] += lcount[k];
        ldsbar();   // srec reads + lclaim update done before next sub-batch
    }
}

__global__ __launch_bounds__(256) void reduce_kernel(
    const unsigned int* __restrict__ pay32,
    const int*    __restrict__ cursor, int cap,
    const float4* __restrict__ pre2,
    const float*  __restrict__ dtp,
    float*        __restrict__ partials,
    int accum, int n) {
    __shared__ float s7[6][TILE];        // 24 KB SoA expanded records
    __shared__ int   lhist[PB];          //  2 KB counts
    __shared__ int   lofs[PB];           //  2 KB offsets -> cursors
    __shared__ float ptab[PB];           //  2 KB per-particle p
    int b   = blockIdx.x >> 2;
    int sb  = blockIdx.x & (NSLICE - 1);
    int tid = threadIdx.x;

    int p0 = (b << PB_SHIFT) + tid;
    int p1 = p0 + 256;
    float pi0 = (p0 < n) ? pre2[2 * (size_t)p0].x : 0.f;
    float pi1 = (p1 < n) ? pre2[2 * (size_t)p1].x : 0.f;
    ptab[tid] = pi0; ptab[tid + 256] = pi1;
    float a0[7] = {0.f, 0.f, 0.f, 0.f, 0.f, 0.f, 0.f};
    float a1[7] = {0.f, 0.f, 0.f, 0.f, 0.f, 0.f, 0.f};

    int r0 = tid * 4;                    // this thread's 4 records per tile
    for (int rg = 0; rg < 2; ++rg) {
        int s = sb + rg * NSLICE;        // regions sb and sb+4
        int cnt = cursor[(size_t)(b * NR + s) * CSTRIDE];
        if (cnt > cap) cnt = cap;
        size_t RB = (size_t)(b * NR + s) * cap * 3;  // dword base of region

        v4f c0v, c1v, c2v, n0v, n1v, n2v;
        if (cnt > 0) {
            int rb = r0;
            int rc_ = (rb + 4 <= cap) ? rb : (cap - 4);
            const v4f* g = (const v4f*)(pay32 + RB + (size_t)rc_ * 3);
            c0v = __builtin_nontemporal_load(g);
            c1v = __builtin_nontemporal_load(g + 1);
            c2v = __builtin_nontemporal_load(g + 2);
        }
        for (int T = 0; T < cnt; T += TILE) {
            lhist[tid] = 0; lhist[tid + 256] = 0;
            // issue next tile's nt loads (in flight across whole pipeline)
            if (T + TILE < cnt) {
                int rb = T + TILE + r0;
                int rc_ = (rb + 4 <= cap) ? rb : (cap - 4);
                const v4f* g = (const v4f*)(pay32 + RB + (size_t)rc_ * 3);
                n0v = __builtin_nontemporal_load(g);
                n1v = __builtin_nontemporal_load(g + 1);
                n2v = __builtin_nontemporal_load(g + 2);
            }
            // decode 4 records; issue pre2[j] gathers EARLY (normal loads: L2)
            int rb = T + r0;
            bool v0 = rb < cnt, v1 = rb + 1 < cnt, v2 = rb + 2 < cnt, v3 = rb + 3 < cnt;
            int jli0 = __float_as_int(c0v.x); float gx0 = c0v.y, gy0 = c0v.z;
            int jli1 = __float_as_int(c0v.w); float gx1 = c1v.x, gy1 = c1v.y;
            int jli2 = __float_as_int(c1v.z); float gx2 = c1v.w, gy2 = c2v.x;
            int jli3 = __float_as_int(c2v.y); float gx3 = c2v.z, gy3 = c2v.w;
            int li0 = jli0 & (PB - 1), li1 = jli1 & (PB - 1);
            int li2 = jli2 & (PB - 1), li3 = jli3 & (PB - 1);
            size_t j0 = v0 ? (size_t)(jli0 >> PB_SHIFT) : 0;
            size_t j1 = v1 ? (size_t)(jli1 >> PB_SHIFT) : 0;
            size_t j2 = v2 ? (size_t)(jli2 >> PB_SHIFT) : 0;
            size_t j3 = v3 ? (size_t)(jli3 >> PB_SHIFT) : 0;
            float4 ja0 = pre2[2 * j0], jb0 = pre2[2 * j0 + 1];
            float4 ja1 = pre2[2 * j1], jb1 = pre2[2 * j1 + 1];
            float4 ja2 = pre2[2 * j2], jb2 = pre2[2 * j2 + 1];
            float4 ja3 = pre2[2 * j3], jb3 = pre2[2 * j3 + 1];
            ldsbar();          // hist zeros + ptab visible
            if (v0) atomicAdd(&lhist[li0], 1);
            if (v1) atomicAdd(&lhist[li1], 1);
            if (v2) atomicAdd(&lhist[li2], 1);
            if (v3) atomicAdd(&lhist[li3], 1);
            ldsbar();
            // exclusive prefix scan of 512 counts by wave 0
            if (tid < 64) {
                int running = 0;
                for (int c = 0; c < 8; ++c) {
                    int orig = lhist[c * 64 + tid];
                    int v = orig;
#pragma unroll
                    for (int off = 1; off < 64; off <<= 1) {
                        int u = __shfl_up(v, off, 64);
                        if (tid >= off) v += u;
                    }
                    lofs[c * 64 + tid] = running + v - orig;
                    running += __shfl(v, 63, 64);
                }
            }
            ldsbar();
            // scatter: expand into 6 SoA b32 arrays in particle-sorted order
#define SCAT(vv, li, jaa, jbb, gxx, gyy)                                     \
            if (vv) {                                                        \
                int sl = atomicAdd(&lofs[li], 1);                            \
                float C0 = jaa.z * gxx;                                      \
                float C1 = jaa.z * gyy;                                      \
                s7[0][sl] = C0;                                              \
                s7[1][sl] = C1;                                              \
                s7[2][sl] = jaa.w * (gxx * gxx + gyy * gyy);                 \
                s7[3][sl] = -(ptab[li] + jaa.x) * jaa.y;                     \
                s7[4][sl] = jbb.x * C0 + jbb.y * C1;                         \
                s7[5][sl] = jbb.z * C0 + jbb.w * C1;                         \
            }
            SCAT(v0, li0, ja0, jb0, gx0, gy0)
            SCAT(v1, li1, ja1, jb1, gx1, gy1)
            SCAT(v2, li2, ja2, jb2, gx2, gy2)
            SCAT(v3, li3, ja3, jb3, gx3, gy3)
#undef SCAT
            ldsbar();
            // gather: contiguous segment per particle, pure-sum b32 reads
            {
                int e0 = lofs[tid], h0 = lhist[tid];
                for (int r = e0 - h0; r < e0; ++r) {
                    float C0 = s7[0][r], C1 = s7[1][r], rc = s7[3][r];
                    a0[0] += C0; a0[1] += C1; a0[2] += s7[2][r];
                    a0[3] += rc * C0; a0[4] += rc * C1;
                    a0[5] += s7[4][r]; a0[6] += s7[5][r];
                }
                int e1 = lofs[tid + 256], h1 = lhist[tid + 256];
                for (int r = e1 - h1; r < e1; ++r) {
                    float C0 = s7[0][r], C1 = s7[1][r], rc = s7[3][r];
                    a1[0] += C0; a1[1] += C1; a1[2] += s7[2][r];
                    a1[3] += rc * C0; a1[4] += rc * C1;
                    a1[5] += s7[4][r]; a1[6] += s7[5][r];
                }
            }
            ldsbar();          // gather done before next tile zeroes lhist
            c0v = n0v; c1v = n1v; c2v = n2v;
        }
    }

    // epilogue: dt scaling + linear i-side corrections; 8-float padded record
    float dt  = dtp[0];
    float dt2 = dt * dt;
    v4f* dst = (v4f*)(partials + ((size_t)b * NSLICE + sb) * (PB * 8));
    {
        float4 va = (p0 < n) ? pre2[2 * (size_t)p0 + 1]
                             : make_float4(0.f, 0.f, 0.f, 0.f);
        float src = dt  * (a0[5] - (va.x * a0[0] + va.y * a0[1]));
        float ker = dt2 * ((va.z * a0[0] + va.w * a0[1]) - a0[6]);
        v4f w0 = {a0[0], a0[1], a0[2], a0[3]};
        v4f w1 = {a0[4], src, ker, 0.f};
        v4f* d = dst + (size_t)tid * 2;
        if (accum) {
            v4f o0 = d[0], o1 = d[1];
            d[0] = w0 + o0; d[1] = w1 + o1;
        } else {
            __builtin_nontemporal_store(w0, d);
            __builtin_nontemporal_store(w1, d + 1);
        }
    }
    {
        float4 va = (p1 < n) ? pre2[2 * (size_t)p1 + 1]
                             : make_float4(0.f, 0.f, 0.f, 0.f);
        float src = dt  * (a1[5] - (va.x * a1[0] + va.y * a1[1]));
        float ker = dt2 * ((va.z * a1[0] + va.w * a1[1]) - a1[6]);
        v4f w0 = {a1[0], a1[1], a1[2], a1[3]};
        v4f w1 = {a1[4], src, ker, 0.f};
        v4f* d = dst + (size_t)(tid + 256) * 2;
        if (accum) {
            v4f o0 = d[0], o1 = d[1];
            d[0] = w0 + o0; d[1] = w1 + o1;
        } else {
            __builtin_nontemporal_store(w0, d);
            __builtin_nontemporal_store(w1, d + 1);
        }
    }
}

// ---- fallback: direct global float atomics ----
__global__ void edge_kernel(const int* __restrict__ nbr,
                            const float* __restrict__ rad,
                            const float2* __restrict__ dirs,
                            const float4* __restrict__ pre2,
                            const float* __restrict__ supp,
                            const float* __restrict__ dtp,
                            float* __restrict__ acc, int E) {
    int e = blockIdx.x * blockDim.x + threadIdx.x;
    if (e >= E) return;
    float h = supp[0], dt = dtp[0];
    float kc = 20.0f * (7.0f / 3.14159265358979323846f) / (h * h * h);
    int i = nbr[e];
    int j = nbr[E + e];
    float  q = rad[e];
    float2 d = dirs[e];
    float om  = 1.0f - q;
    float mag = kc * q * om * om * om;
    float gx = -d.x * mag;
    float gy = -d.y * mag;
    float g2 = gx * gx + gy * gy;
    float4 ja = pre2[2 * (size_t)j];      // {p, r, aa, aa2m}
    float4 jb = pre2[2 * (size_t)j + 1];
    float4 ia = pre2[2 * (size_t)i];
    float4 ib = pre2[2 * (size_t)i + 1];
    float aaj = ja.z;
    float m   = ja.y * aaj;
    float pp  = -m * (ia.x + ja.x);
    float vdotg = (ib.x - jb.x) * gx + (ib.y - jb.y) * gy;
    float adotg = (ib.z - jb.z) * gx + (ib.w - jb.w) * gy;
    float* base = acc + (size_t)i * 8;
    atomicAdd(base + 0, aaj * gx);
    atomicAdd(base + 1, aaj * gy);
    atomicAdd(base + 2, ja.w * g2);
    atomicAdd(base + 3, pp * gx);
    atomicAdd(base + 4, pp * gy);
    atomicAdd(base + 5, -dt * aaj * vdotg);
    atomicAdd(base + 6, dt * dt * aaj * adotg);
}

__global__ __launch_bounds__(256) void fin_kernel(
    const float* __restrict__ area,
    const float* __restrict__ actualArea,
    const float* __restrict__ restDensity,
    const float* __restrict__ dtp,
    const float* __restrict__ data, int mode, int nslice,
    float* __restrict__ out, int n) {
    int t = blockIdx.x * blockDim.x + threadIdx.x;
    if (t >= n) return;
    float s0 = 0, s1 = 0, s2 = 0, s3 = 0, s4 = 0, s5 = 0, s6 = 0;
    if (mode == 0) {
        const v4f* base = (const v4f*)data
            + ((size_t)(t >> PB_SHIFT) * NSLICE) * (PB * 2)
            + (size_t)(t & (PB - 1)) * 2;
        for (int s = 0; s < nslice; ++s) {
            v4f q0 = __builtin_nontemporal_load(base + (size_t)s * (PB * 2));
            v4f q1 = __builtin_nontemporal_load(base + (size_t)s * (PB * 2) + 1);
            s0 += q0.x; s1 += q0.y; s2 += q0.z; s3 += q0.w;
            s4 += q1.x; s5 += q1.y; s6 += q1.z;
        }
    } else {
        const float* a = data + (size_t)t * 8;
        s0 = a[0]; s1 = a[1]; s2 = a[2]; s3 = a[3];
        s4 = a[4]; s5 = a[5]; s6 = a[6];
    }
    float dt   = dtp[0];
    float fac  = -dt * dt * actualArea[t];
    float mass = area[t] * restDensity[t];
    float alpha = fac / mass * (s0 * s0 + s1 * s1) + fac * s2;
    float* o = out + (size_t)t * 5;
    o[0] = alpha;
    o[1] = s3;
    o[2] = s4;
    o[3] = s5;
    o[4] = s6;
}

extern "C" void kernel_launch(void* const* d_in, const int* in_sizes, int n_in,
                              void* d_out, int out_size, void* d_ws, size_t ws_size,
                              hipStream_t stream) {
    const float* area        = (const float*)d_in[0];
    const float* actualArea  = (const float*)d_in[1];
    const float* restDensity = (const float*)d_in[2];
    const float* density     = (const float*)d_in[3];
    const float* pressure2   = (const float*)d_in[4];
    const float2* vel        = (const float2*)d_in[5];
    const float2* accel      = (const float2*)d_in[6];
    const float* rad         = (const float*)d_in[7];
    const float2* dirs       = (const float2*)d_in[8];
    const int*   nbr         = (const int*)d_in[9];
    const float* supp        = (const float*)d_in[10];
    const float* dtp         = (const float*)d_in[11];
    float* out = (float*)d_out;

    int N = in_sizes[0];
    int E = in_sizes[7];
    int nb = (N + PB - 1) >> PB_SHIFT;   // 512 for N=262144

    size_t sz_cur   = (size_t)nb * NR * CSTRIDE * 8 * sizeof(int);
    size_t off_pre  = align256(sz_cur);
    size_t sz_pre   = (size_t)N * 8 * sizeof(float);
    size_t off_part = align256(off_pre + sz_pre);
    size_t sz_partA = (size_t)nb * NSLICE * PB * 8 * sizeof(float);
    size_t sz_partB = (size_t)N * 8 * sizeof(float);   // fallback acc layout
    size_t sz_part  = sz_partA > sz_partB ? sz_partA : sz_partB;
    size_t off_pay  = align256(off_part + sz_part);

    int* cursor     = (int*)d_ws;
    float4* pre2    = (float4*)((char*)d_ws + off_pre);
    float* partials = (float*)((char*)d_ws + off_part);

    // pick chunking so payload fits (12B records, NR regions per bucket)
    int nchunk = 0, cap = 0;
    if (nb <= 512 && ws_size > off_pay) {
        for (int c = 1; c <= 8; c *= 2) {
            long long Ec = (E + c - 1) / c;
            double mean = (double)Ec / ((double)nb * NR);
            long long need = (long long)(mean + 8.0 * sqrt(mean) + 64.0);
            need = (need + 63) & ~63ll;
            if (off_pay + (size_t)nb * NR * need * 12 <= ws_size) {
                nchunk = c; cap = (int)need; break;
            }
        }
    }

    int bs = 256;
    int grid_n = (N + bs - 1) / bs;
    if (nchunk > 0) {
        unsigned int* pay32 = (unsigned int*)((char*)d_ws + off_pay);
        hipMemsetAsync(d_ws, 0, sz_cur, stream);   // zero cursors
        int Ec  = (E + nchunk - 1) / nchunk;
        for (int c = 0; c < nchunk; ++c) {
            int es = c * Ec;
            int ee = es + Ec; if (ee > E) ee = E;
            if (es >= ee) break;
            int* curC = cursor + (size_t)c * nb * NR * CSTRIDE;
            int nblk = (ee - es + BIN_EDGES - 1) / BIN_EDGES;
            int ppb  = (N + nblk - 1) / nblk;
            bin_kernel<<<nblk, bs, 0, stream>>>(
                nbr, rad, dirs, supp,
                area, actualArea, restDensity, density, pressure2, vel, accel,
                pre2, (c == 0) ? 1 : 0, ppb, N,
                curC, pay32, cap, nb, es, ee, E);
            reduce_kernel<<<nb * NSLICE, bs, 0, stream>>>(
                pay32, curC, cap, pre2, dtp, partials, (c > 0) ? 1 : 0, N);
        }
        fin_kernel<<<grid_n, bs, 0, stream>>>(
            area, actualArea, restDensity, dtp, partials, 0, NSLICE, out, N);
    } else {
        float* acc = partials;  // [N,8] at off_part
        pre_kernel<<<grid_n, bs, 0, stream>>>(
            area, actualArea, restDensity, density, pressure2, vel, accel,
            pre2, acc, N * 8, N);
        edge_kernel<<<(E + bs - 1) / bs, bs, 0, stream>>>(
            nbr, rad, dirs, pre2, supp, dtp, acc, E);
        fin_kernel<<<grid_n, bs, 0, stream>>>(
            area, actualArea, restDensity, dtp, acc, 1, 0, out, N);
    }
}